// Round 3
// baseline (228.994 us; speedup 1.0000x reference)
//
#include <hip/hip_runtime.h>

// Self_Attn_3D: B=8, H=W=64 (N=4096 tokens), C_IN=256, C_QK=32.
// out[b,n] = gamma * sum_m softmax(q_n.k_m) * vbar[b,m] + xbar[b,n]
//   vbar = x @ mean_j(Wv) + mean(bv);  xbar = mean_c(x)
// (channel-mean commutes through attention output -> scalar-V flash attention)
//
// R5: R4's hipLaunchCooperativeKernel silently failed under graph capture
// (out stayed zero -> absmax 0.32 == ||ref||_inf). Same fusion, new
// mechanism: plain launch + manual device-scope-atomic grid barrier.
// Co-residency guaranteed: 512 blocks x 256thr, __launch_bounds__(256,2)
// (VGPR<=128 -> 2 blocks/CU), LDS 33.8KB <= 80KB. Counters zeroed by a
// captured hipMemsetAsync. Bounded spin converts deadlock -> wrong-answer.

typedef _Float16 half8  __attribute__((ext_vector_type(8)));
typedef _Float16 half4v __attribute__((ext_vector_type(4)));
typedef float    f32x4  __attribute__((ext_vector_type(4)));

#define LOG2E 1.4426950408889634f

#if __has_builtin(__builtin_amdgcn_exp2f)
#define EXP2(x) __builtin_amdgcn_exp2f(x)
#else
#define EXP2(x) exp2f(x)
#endif

#define NBLOCKS 512

// device-scope sense-free barrier: one counter per barrier instance,
// re-zeroed each iteration by the captured memset node.
__device__ __forceinline__ void grid_barrier(int* cnt) {
  __syncthreads();
  if (threadIdx.x == 0) {
    __threadfence();   // release: L2 writeback (agent scope)
    __hip_atomic_fetch_add(cnt, 1, __ATOMIC_ACQ_REL, __HIP_MEMORY_SCOPE_AGENT);
    long t = 0;
    while (__hip_atomic_load(cnt, __ATOMIC_ACQUIRE, __HIP_MEMORY_SCOPE_AGENT) < NBLOCKS) {
      if (++t > (1L << 26)) break;   // deadlock -> give up (fails check, not hang)
      __builtin_amdgcn_s_sleep(1);
    }
    __threadfence();   // acquire: L2 invalidate (agent scope)
  }
  __syncthreads();
}

// ---------------------------------------------------------------------------
// fused: grid 512 x 256, plain launch, 2 blocks/CU co-resident.
// phase A (prep): blocks 0-63 build Wfr = [Wq|Wk] f16 in MFMA-B-fragment
//   order Wfr[((ch*4+quad)*64+col)*8+j] = W[c=ch*32+quad*8+j][col];
//   blocks 64-127 build wvbar[256] = row-mean(Wv); block 128 bvbar=mean(bv).
// phase B (proj): block = one 64-token tile. Qh=(x@Wq+bq)*log2e (f16),
//   Kh=x@Wk+bk (f16), vbar, xbar (f32). MFMA A from LDS, B direct from Wfr.
// phase C (flash): block = (b, qtile). Scalar-V attention, barrier-free.
//   K B-fragments read DIRECTLY from global (layout == MFMA B operand,
//   1 KB coalesced per load, L2-hot). Static-max softmax via MFMA C = -88.
// ---------------------------------------------------------------------------
__global__ __launch_bounds__(256, 2) void fused_kernel(
    const float* __restrict__ x,
    const float* __restrict__ Wq, const float* __restrict__ bq,
    const float* __restrict__ Wk, const float* __restrict__ bk,
    const float* __restrict__ Wv, const float* __restrict__ bv,
    const float* __restrict__ gamma,
    _Float16* __restrict__ Wfr, float* __restrict__ wvbar, float* __restrict__ bvbar,
    _Float16* __restrict__ Qh, _Float16* __restrict__ Kh,
    float* __restrict__ vbarA, float* __restrict__ xbarA,
    int* __restrict__ gbar,
    float* __restrict__ out)
{
  __shared__ _Float16 XT[64 * 264];   // 64 tokens x 256 f16, stride 264 (bank spread)
  int tid = threadIdx.x, blk = blockIdx.x;
  int lane = tid & 63, w = tid >> 6;
  int l15 = lane & 15, quad = lane >> 4;

  // ---------------- phase A: prep ----------------
  if (blk < 64) {
    int col = blk, c = tid;
    float v = (col < 32) ? Wq[c * 32 + col] : Wk[c * 32 + (col - 32)];
    int ch = c >> 5, qd = (c >> 3) & 3, j = c & 7;
    Wfr[(size_t)((ch * 4 + qd) * 64 + col) * 8 + j] = (_Float16)v;
  } else if (blk < 128) {
    // one wave per Wv row: row-mean over 256 cols
    int row = (blk - 64) * 4 + w;
    const float* p = Wv + (size_t)row * 256 + lane * 4;
    float s = p[0] + p[1] + p[2] + p[3];
    #pragma unroll
    for (int off = 32; off >= 1; off >>= 1) s += __shfl_xor(s, off);
    if (lane == 0) wvbar[row] = s * (1.0f / 256.0f);
  } else if (blk == 128) {
    if (tid < 64) {
      const float* p = bv + tid * 4;
      float s = p[0] + p[1] + p[2] + p[3];
      #pragma unroll
      for (int off = 32; off >= 1; off >>= 1) s += __shfl_xor(s, off);
      if (tid == 0) bvbar[0] = s * (1.0f / 256.0f);
    }
  }

  grid_barrier(gbar + 0);

  // ---------------- phase B: proj (tile = blk) ----------------
  {
    size_t tok0 = (size_t)blk * 64;

    // stage x -> XT (f32->f16), fully coalesced global reads
    const float4* xg4 = (const float4*)x;
    #pragma unroll
    for (int i = 0; i < 16; ++i) {
      int f = i * 256 + tid;            // 0..4095 float4s in this tile
      int tok = f >> 6, c4 = f & 63;
      float4 v = xg4[(size_t)blk * 4096 + f];
      half4v h;
      h.x = (_Float16)v.x; h.y = (_Float16)v.y; h.z = (_Float16)v.z; h.w = (_Float16)v.w;
      *(half4v*)&XT[tok * 264 + c4 * 4] = h;
    }
    __syncthreads();

    // vbar / xbar: one thread per token (f16-rounded x is fine: error ~1e-5)
    if (tid < 64) {
      float vs = 0.f, xs = 0.f;
      #pragma unroll 4
      for (int g = 0; g < 32; ++g) {
        half8 h = *(const half8*)&XT[tid * 264 + g * 8];
        #pragma unroll
        for (int j = 0; j < 8; ++j) {
          float xv = (float)h[j];
          vs += xv * wvbar[g * 8 + j];   // uniform -> s_load
          xs += xv;
        }
      }
      vbarA[tok0 + tid] = vs + bvbar[0];
      xbarA[tok0 + tid] = xs * (1.0f / 256.0f);
    }

    // MFMA: 64 tokens x 64 outputs, K=256 in 8 chunks of 32
    f32x4 acc[4] = {(f32x4){0,0,0,0},(f32x4){0,0,0,0},(f32x4){0,0,0,0},(f32x4){0,0,0,0}};
    #pragma unroll
    for (int ch = 0; ch < 8; ++ch) {
      half8 a = *(const half8*)&XT[(w * 16 + l15) * 264 + ch * 32 + quad * 8];
      #pragma unroll
      for (int ct = 0; ct < 4; ++ct) {
        half8 bf = *(const half8*)(Wfr + (size_t)((ch * 4 + quad) * 64 + ct * 16 + l15) * 8);
        acc[ct] = __builtin_amdgcn_mfma_f32_16x16x32_f16(a, bf, acc[ct], 0, 0, 0);
      }
    }
    // epilogue: D layout col=lane&15, row=quad*4+reg
    #pragma unroll
    for (int ct = 0; ct < 4; ++ct) {
      int col = ct * 16 + l15;
      #pragma unroll
      for (int r = 0; r < 4; ++r) {
        int token = w * 16 + quad * 4 + r;
        if (ct < 2) {
          float val = (acc[ct][r] + bq[col]) * LOG2E;      // fold log2e into Q
          Qh[(tok0 + token) * 32 + col] = (_Float16)val;
        } else {
          float val = acc[ct][r] + bk[col - 32];
          Kh[(tok0 + token) * 32 + (col - 32)] = (_Float16)val;
        }
      }
    }
  }

  grid_barrier(gbar + 1);

  // ---------------- phase C: flash (block = (b, qtile)) ----------------
  {
    int b = blk >> 6, qt = blk & 63;

    const _Float16* Qb = Qh + (size_t)b * 4096 * 32;
    const _Float16* Kb = Kh + (size_t)b * 4096 * 32;
    const float* vb = vbarA + (size_t)b * 4096;

    // per-wave Q fragment: A[m=lane&15][k=quad*8+j]
    int qrow = qt * 64 + w * 16 + l15;
    half8 aq = *(const half8*)(Qb + (size_t)qrow * 32 + quad * 8);

    float lacc[4] = {0, 0, 0, 0}, oacc[4] = {0, 0, 0, 0};
    const f32x4 cinit = {-88.f, -88.f, -88.f, -88.f};

    // B-fragment address for this lane: K row (ct*16+l15), halves quad*8..+7
    const _Float16* kfrag = Kb + (size_t)l15 * 32 + quad * 8;
    const float* vfrag = vb + l15;

    #pragma unroll 2
    for (int kt = 0; kt < 64; ++kt) {
      half8 bk8[4];
      float vbl[4];
      #pragma unroll
      for (int ct = 0; ct < 4; ++ct) {
        bk8[ct] = *(const half8*)(kfrag + (size_t)(kt * 64 + ct * 16) * 32);
        vbl[ct] = vfrag[kt * 64 + ct * 16];
      }
      f32x4 sc[4];
      #pragma unroll
      for (int ct = 0; ct < 4; ++ct)
        sc[ct] = __builtin_amdgcn_mfma_f32_16x16x32_f16(aq, bk8[ct], cinit, 0, 0, 0);
      #pragma unroll
      for (int r = 0; r < 4; ++r) {   // rows quad*4+r; cols ct*16+(lane&15)
        float p0 = EXP2(sc[0][r]), p1 = EXP2(sc[1][r]);
        float p2 = EXP2(sc[2][r]), p3 = EXP2(sc[3][r]);
        lacc[r] += (p0 + p1) + (p2 + p3);
        oacc[r] += ((p0 * vbl[0] + p1 * vbl[1]) + (p2 * vbl[2] + p3 * vbl[3]));
      }
    }

    // reduce partials across the 16 lanes sharing a quad
    #pragma unroll
    for (int r = 0; r < 4; ++r) {
      #pragma unroll
      for (int off = 1; off < 16; off <<= 1) {
        lacc[r] += __shfl_xor(lacc[r], off);
        oacc[r] += __shfl_xor(oacc[r], off);
      }
    }
    if (l15 == 0) {
      float g = gamma[0];
      #pragma unroll
      for (int r = 0; r < 4; ++r) {
        int row = qt * 64 + w * 16 + quad * 4 + r;
        out[(size_t)b * 4096 + row] = g * (oacc[r] / lacc[r]) + xbarA[(size_t)b * 4096 + row];
      }
    }
  }
}

// ---------------------------------------------------------------------------
extern "C" void kernel_launch(void* const* d_in, const int* in_sizes, int n_in,
                              void* d_out, int out_size, void* d_ws, size_t ws_size,
                              hipStream_t stream)
{
  const float* x     = (const float*)d_in[0];
  const float* Wq    = (const float*)d_in[1];
  const float* bq    = (const float*)d_in[2];
  const float* Wk    = (const float*)d_in[3];
  const float* bk    = (const float*)d_in[4];
  const float* Wv    = (const float*)d_in[5];
  const float* bv    = (const float*)d_in[6];
  const float* gamma = (const float*)d_in[7];
  float* out = (float*)d_out;

  char* ws = (char*)d_ws;                          // needs ~8.1 MB
  _Float16* Wfr  = (_Float16*)(ws);                // 32 KB
  float* wvbar   = (float*)(ws + 32768);           // 1 KB
  float* bvbar   = (float*)(ws + 33792);           // 4 B
  _Float16* Qh   = (_Float16*)(ws + 65536);        // 2 MB
  _Float16* Kh   = (_Float16*)(ws + 65536 + 2097152);        // 2 MB
  float* vbarA   = (float*)(ws + 65536 + 4194304);           // 128 KB
  float* xbarA   = (float*)(ws + 65536 + 4194304 + 131072);  // 128 KB
  int*   gbar    = (int*)(ws + 8388608);                     // 2 x int barrier counters

  hipMemsetAsync(gbar, 0, 2 * sizeof(int), stream);
  fused_kernel<<<NBLOCKS, 256, 0, stream>>>(
      x, Wq, bq, Wk, bk, Wv, bv, gamma,
      Wfr, wvbar, bvbar, Qh, Kh, vbarA, xbarA, gbar, out);
}

// Round 4
// 145.022 us; speedup vs baseline: 1.5790x; 1.5790x over previous
//
#include <hip/hip_runtime.h>

// Self_Attn_3D: B=8, H=W=64 (N=4096 tokens), C_IN=256, C_QK=32.
// out[b,n] = gamma * sum_m softmax(q_n.k_m) * vbar[b,m] + xbar[b,n]
//   vbar = x @ mean_j(Wv) + mean(bv);  xbar = mean_c(x)
// (channel-mean commutes through attention output -> scalar-V flash attention)
//
// R6: R3/R5 showed (a) total real compute is ~20us (VALUBusy 8.6% x 160us),
// (b) a manual grid barrier costs ~140us (per-poll acquire/L2-inv storm) --
// abandoned. Structural win instead: prep merged INTO proj by redundant
// per-block W staging (Wq/Wk fragments -> LDS with XOR-col swizzle to kill
// the 16-way u16 scatter-write conflict; wvbar row-means computed per block;
// all W reads are L2-resident broadcasts). 2 dispatches, no sync, no memset.
// Flash reverted to the proven R0 form (125.8us ensemble).

typedef _Float16 half8  __attribute__((ext_vector_type(8)));
typedef _Float16 half4v __attribute__((ext_vector_type(4)));
typedef float    f32x4  __attribute__((ext_vector_type(4)));

#define LOG2E 1.4426950408889634f

#if __has_builtin(__builtin_amdgcn_exp2f)
#define EXP2(x) __builtin_amdgcn_exp2f(x)
#else
#define EXP2(x) exp2f(x)
#endif

// ---------------------------------------------------------------------------
// proj (self-contained): per 64-token tile:
//   Qh=(x@Wq+bq)*log2e (f16), Kh=x@Wk+bk (f16), vbar, xbar (f32).
// W-fragments staged per block into LDS:
//   WF[ch4q][col ^ (ch4q&7)][j] = W[c][col], c = tid, ch4q = tid>>3, j = tid&7
//   (XOR swizzle: writer lanes vary ch4q&7/j at fixed col -> banks
//    ((col^ch4q)&7)*4 + j/2 cover all 32, 2-way = free; reader b128 lanes
//    vary l15/quad -> uniform over the 8 bank-groups, conflict-free.)
// wvbar: thread t = row-mean(Wv[t,:]) -> LDS.  grid 512 x 256
// ---------------------------------------------------------------------------
__global__ __launch_bounds__(256) void proj_kernel(
    const float* __restrict__ x,
    const float* __restrict__ Wq, const float* __restrict__ bq,
    const float* __restrict__ Wk, const float* __restrict__ bk,
    const float* __restrict__ Wv, const float* __restrict__ bv,
    _Float16* __restrict__ Qh, _Float16* __restrict__ Kh,
    float* __restrict__ vbarO, float* __restrict__ xbarO)
{
  __shared__ _Float16 XT[64 * 264];   // 64 tokens x 256 f16, stride 264 (bank spread)
  __shared__ _Float16 WF[16384];      // [Wq|Wk] fragments, 32 KB, col-swizzled
  __shared__ float    wvb[256];       // row-means of Wv
  int tid = threadIdx.x, blk = blockIdx.x;
  size_t tok0 = (size_t)blk * 64;
  int lane = tid & 63, w = tid >> 6;
  int l15 = lane & 15, quad = lane >> 4;

  // stage x -> XT (f32->f16), fully coalesced global reads
  const float4* xg4 = (const float4*)x;
  #pragma unroll
  for (int i = 0; i < 16; ++i) {
    int f = i * 256 + tid;            // 0..4095 float4s in this tile
    int tok = f >> 6, c4 = f & 63;
    float4 v = xg4[(size_t)blk * 4096 + f];
    half4v h;
    h.x = (_Float16)v.x; h.y = (_Float16)v.y; h.z = (_Float16)v.z; h.w = (_Float16)v.w;
    *(half4v*)&XT[tok * 264 + c4 * 4] = h;
  }

  // stage [Wq|Wk] row tid -> WF fragments (L2-broadcast reads, 64 KB/block)
  {
    int c = tid;                       // source row = channel
    int ch4q = c >> 3, j = c & 7;      // fragment coords
    int swz = ch4q & 7;
    const float4* wq4 = (const float4*)(Wq + (size_t)c * 32);
    const float4* wk4 = (const float4*)(Wk + (size_t)c * 32);
    #pragma unroll
    for (int i = 0; i < 8; ++i) {
      float4 q = wq4[i], k = wk4[i];
      #pragma unroll
      for (int e = 0; e < 4; ++e) {
        int col = i * 4 + e;
        float qv = (&q.x)[e], kv = (&k.x)[e];
        WF[ch4q * 512 + ((col)      ^ swz) * 8 + j] = (_Float16)qv;
        WF[ch4q * 512 + ((col + 32) ^ swz) * 8 + j] = (_Float16)kv;
      }
    }
  }

  // wvbar[tid] = mean(Wv[tid, :]) (L2-broadcast after first touch)
  {
    const float4* p = (const float4*)(Wv + (size_t)tid * 256);
    float sx = 0.f, sy = 0.f, sz = 0.f, sw = 0.f;
    #pragma unroll 8
    for (int i = 0; i < 64; ++i) {
      float4 v = p[i];
      sx += v.x; sy += v.y; sz += v.z; sw += v.w;
    }
    wvb[tid] = (sx + sy + sz + sw) * (1.0f / 256.0f);
  }
  __syncthreads();

  // vbar / xbar: one thread per token (f16-rounded x is fine: error ~1e-5)
  if (tid < 64) {
    float vs = 0.f, xs = 0.f;
    #pragma unroll 4
    for (int g = 0; g < 32; ++g) {
      half8 h = *(const half8*)&XT[tid * 264 + g * 8];
      #pragma unroll
      for (int j = 0; j < 8; ++j) {
        float xv = (float)h[j];
        vs += xv * wvb[g * 8 + j];     // uniform -> LDS broadcast
        xs += xv;
      }
    }
    float bs = 0.f;
    const float4* b4 = (const float4*)bv;   // 1 KB, broadcast
    #pragma unroll 8
    for (int i = 0; i < 64; ++i) {
      float4 v = b4[i];
      bs += (v.x + v.y) + (v.z + v.w);
    }
    vbarO[tok0 + tid] = vs + bs * (1.0f / 256.0f);
    xbarO[tok0 + tid] = xs * (1.0f / 256.0f);
  }

  // MFMA: 64 tokens x 64 outputs, K=256 in 8 chunks of 32, B from WF (LDS)
  f32x4 acc[4] = {(f32x4){0,0,0,0},(f32x4){0,0,0,0},(f32x4){0,0,0,0},(f32x4){0,0,0,0}};
  #pragma unroll
  for (int ch = 0; ch < 8; ++ch) {
    half8 a = *(const half8*)&XT[(w * 16 + l15) * 264 + ch * 32 + quad * 8];
    int c4q = ch * 4 + quad, swz = c4q & 7;
    #pragma unroll
    for (int ct = 0; ct < 4; ++ct) {
      half8 bf = *(const half8*)&WF[c4q * 512 + ((ct * 16 + l15) ^ swz) * 8];
      acc[ct] = __builtin_amdgcn_mfma_f32_16x16x32_f16(a, bf, acc[ct], 0, 0, 0);
    }
  }
  // epilogue: D layout col=lane&15, row=quad*4+reg
  #pragma unroll
  for (int ct = 0; ct < 4; ++ct) {
    int col = ct * 16 + l15;
    #pragma unroll
    for (int r = 0; r < 4; ++r) {
      int token = w * 16 + quad * 4 + r;
      if (ct < 2) {
        float val = (acc[ct][r] + bq[col]) * LOG2E;      // fold log2e into Q
        Qh[(tok0 + token) * 32 + col] = (_Float16)val;
      } else {
        float val = acc[ct][r] + bk[col - 32];
        Kh[(tok0 + token) * 32 + (col - 32)] = (_Float16)val;
      }
    }
  }
}

// ---------------------------------------------------------------------------
// flash (R0-proven): scalar-V attention, barrier-free. One block = 64 Q-rows
// of one batch; 4 independent waves x 16 rows. K B-fragments read DIRECTLY
// from global (layout matches MFMA B operand; 1 KB coalesced per load,
// L2-hot). Static-max softmax: s = q.k*log2e - 88 via MFMA C bias; p = 2^s.
// grid 512 x 256
// ---------------------------------------------------------------------------
__global__ __launch_bounds__(256) void flash_kernel(
    const _Float16* __restrict__ Qh, const _Float16* __restrict__ Kh,
    const float* __restrict__ vbar, const float* __restrict__ xbar,
    const float* __restrict__ gamma, float* __restrict__ out)
{
  int tid = threadIdx.x, blk = blockIdx.x;
  int b = blk >> 6, qt = blk & 63;
  int lane = tid & 63, w = tid >> 6;
  int l15 = lane & 15, quad = lane >> 4;

  const _Float16* Qb = Qh + (size_t)b * 4096 * 32;
  const _Float16* Kb = Kh + (size_t)b * 4096 * 32;
  const float* vb = vbar + (size_t)b * 4096;

  // per-wave Q fragment: A[m=lane&15][k=quad*8+j]
  int qrow = qt * 64 + w * 16 + l15;
  half8 aq = *(const half8*)(Qb + (size_t)qrow * 32 + quad * 8);

  float lacc[4] = {0, 0, 0, 0}, oacc[4] = {0, 0, 0, 0};
  const f32x4 cinit = {-88.f, -88.f, -88.f, -88.f};

  // B-fragment address for this lane: K row (ct*16+l15), halves quad*8..+7
  const _Float16* kfrag = Kb + (size_t)l15 * 32 + quad * 8;
  const float* vfrag = vb + l15;

  #pragma unroll 2
  for (int kt = 0; kt < 64; ++kt) {
    half8 bk8[4];
    float vbl[4];
    #pragma unroll
    for (int ct = 0; ct < 4; ++ct) {
      bk8[ct] = *(const half8*)(kfrag + (size_t)(kt * 64 + ct * 16) * 32);
      vbl[ct] = vfrag[kt * 64 + ct * 16];
    }
    f32x4 sc[4];
    #pragma unroll
    for (int ct = 0; ct < 4; ++ct)
      sc[ct] = __builtin_amdgcn_mfma_f32_16x16x32_f16(aq, bk8[ct], cinit, 0, 0, 0);
    #pragma unroll
    for (int r = 0; r < 4; ++r) {   // rows quad*4+r; cols ct*16+(lane&15)
      float p0 = EXP2(sc[0][r]), p1 = EXP2(sc[1][r]);
      float p2 = EXP2(sc[2][r]), p3 = EXP2(sc[3][r]);
      lacc[r] += (p0 + p1) + (p2 + p3);
      oacc[r] += ((p0 * vbl[0] + p1 * vbl[1]) + (p2 * vbl[2] + p3 * vbl[3]));
    }
  }

  // reduce partials across the 16 lanes sharing a quad
  #pragma unroll
  for (int r = 0; r < 4; ++r) {
    #pragma unroll
    for (int off = 1; off < 16; off <<= 1) {
      lacc[r] += __shfl_xor(lacc[r], off);
      oacc[r] += __shfl_xor(oacc[r], off);
    }
  }
  if (l15 == 0) {
    float g = gamma[0];
    #pragma unroll
    for (int r = 0; r < 4; ++r) {
      int row = qt * 64 + w * 16 + quad * 4 + r;
      out[(size_t)b * 4096 + row] = g * (oacc[r] / lacc[r]) + xbar[(size_t)b * 4096 + row];
    }
  }
}

// ---------------------------------------------------------------------------
extern "C" void kernel_launch(void* const* d_in, const int* in_sizes, int n_in,
                              void* d_out, int out_size, void* d_ws, size_t ws_size,
                              hipStream_t stream)
{
  const float* x     = (const float*)d_in[0];
  const float* Wq    = (const float*)d_in[1];
  const float* bq    = (const float*)d_in[2];
  const float* Wk    = (const float*)d_in[3];
  const float* bk    = (const float*)d_in[4];
  const float* Wv    = (const float*)d_in[5];
  const float* bv    = (const float*)d_in[6];
  const float* gamma = (const float*)d_in[7];
  float* out = (float*)d_out;

  char* ws = (char*)d_ws;                          // needs ~4.4 MB
  _Float16* Qh   = (_Float16*)(ws);                          // 2 MB
  _Float16* Kh   = (_Float16*)(ws + 2097152);                // 2 MB
  float* vbarA   = (float*)(ws + 4194304);                   // 128 KB
  float* xbarA   = (float*)(ws + 4194304 + 131072);          // 128 KB

  proj_kernel<<<512, 256, 0, stream>>>(x, Wq, bq, Wk, bk, Wv, bv, Qh, Kh, vbarA, xbarA);
  flash_kernel<<<512, 256, 0, stream>>>(Qh, Kh, vbarA, xbarA, gamma, out);
}